// Round 5
// baseline (169.585 us; speedup 1.0000x reference)
//
#include <hip/hip_runtime.h>

constexpr int IN_F  = 32;
constexpr int OUT_F = 128;
constexpr int BLOCK = 256;
constexpr int WAVES = BLOCK / 64;

using f32x2  = __attribute__((ext_vector_type(2)))  float;
using f32x16 = __attribute__((ext_vector_type(16))) float;

// Force a wave-uniform pointer into SGPRs so "s" asm constraints are satisfiable.
__device__ __forceinline__ const float* uniform_ptr(const float* p) {
    const uint64_t u = reinterpret_cast<uint64_t>(p);
    const uint32_t lo = __builtin_amdgcn_readfirstlane((uint32_t)u);
    const uint32_t hi = __builtin_amdgcn_readfirstlane((uint32_t)(u >> 32));
    return reinterpret_cast<const float*>(((uint64_t)hi << 32) | lo);
}

// Load one 32-float x row into 32 SGPRs via the scalar pipe (lgkmcnt, not vmcnt).
__device__ __forceinline__ void sload_row(const float* p, f32x16& lo, f32x16& hi) {
    const float* up = uniform_ptr(p);
    asm volatile("s_load_dwordx16 %0, %2, 0x0\n\t"
                 "s_load_dwordx16 %1, %2, 0x40"
                 : "=&s"(lo), "=&s"(hi)
                 : "s"(up));
}

__device__ __forceinline__ void wait_smem() {
    asm volatile("s_waitcnt lgkmcnt(0)" ::: "memory");
    __builtin_amdgcn_sched_barrier(0);   // SMEM is not HW-interlocked; pin consumers below
}

__device__ __forceinline__ void compute_row(const f32x16& lo, const f32x16& hi,
                                            const f32x2* c0p, const f32x2* c1p,
                                            float c2a, float c2b, float iv0, float iv1,
                                            float* orow, int o0)
{
    f32x2 a0 = {0.f, 0.f}, a1 = {0.f, 0.f}, s2 = {0.f, 0.f};
    #pragma unroll
    for (int j = 0; j < 8; ++j) {
        const f32x2 xp = { lo[2*j], lo[2*j+1] };     // consecutive SGPR pair
        a0 = __builtin_elementwise_fma(xp, c0p[j], a0);
        a1 = __builtin_elementwise_fma(xp, c1p[j], a1);
        s2 = __builtin_elementwise_fma(xp, xp, s2);
    }
    #pragma unroll
    for (int j = 0; j < 8; ++j) {
        const f32x2 xp = { hi[2*j], hi[2*j+1] };
        a0 = __builtin_elementwise_fma(xp, c0p[8+j], a0);
        a1 = __builtin_elementwise_fma(xp, c1p[8+j], a1);
        s2 = __builtin_elementwise_fma(xp, xp, s2);
    }
    const float x2   = s2.x + s2.y;
    const float acc0 = a0.x + a0.y;
    const float acc1 = a1.x + a1.y;
    const float t0 = fmaxf(fmaf(-2.0f, acc0, x2 + c2a), 0.0f);
    const float t1 = fmaxf(fmaf(-2.0f, acc1, x2 + c2b), 0.0f);
    f32x2 o;
    o.x = __expf(-t0 * iv0);
    o.y = __expf(-t1 * iv1);
    // lane l writes bytes [8l, 8l+8): 512 B contiguous per wave per row
    __builtin_nontemporal_store(o, reinterpret_cast<f32x2*>(orow + o0));
}

__global__ __launch_bounds__(BLOCK, 4)
void rbf_kernel(const float* __restrict__ x,
                const float* __restrict__ centres,
                const float* __restrict__ log_sigmas,
                float* __restrict__ out,
                int rows_per_wave)
{
    const int tid  = threadIdx.x;
    const int wv   = tid >> 6;
    const int lane = tid & 63;

    // ---- per-lane centres (outputs 2*lane, 2*lane+1) as f32x2 pairs ----
    const int o0 = lane * 2;
    f32x2 c0p[IN_F / 2], c1p[IN_F / 2];
    float c2a = 0.f, c2b = 0.f;
    #pragma unroll
    for (int kc = 0; kc < IN_F / 4; ++kc) {
        const float4 a = *reinterpret_cast<const float4*>(centres + (size_t)(o0 + 0) * IN_F + kc * 4);
        const float4 b = *reinterpret_cast<const float4*>(centres + (size_t)(o0 + 1) * IN_F + kc * 4);
        c0p[2*kc + 0] = (f32x2){a.x, a.y};
        c0p[2*kc + 1] = (f32x2){a.z, a.w};
        c1p[2*kc + 0] = (f32x2){b.x, b.y};
        c1p[2*kc + 1] = (f32x2){b.z, b.w};
        c2a = fmaf(a.x,a.x,c2a); c2a = fmaf(a.y,a.y,c2a);
        c2a = fmaf(a.z,a.z,c2a); c2a = fmaf(a.w,a.w,c2a);
        c2b = fmaf(b.x,b.x,c2b); c2b = fmaf(b.y,b.y,c2b);
        c2b = fmaf(b.z,b.z,c2b); c2b = fmaf(b.w,b.w,c2b);
    }
    const float iv0 = __expf(-2.0f * log_sigmas[o0 + 0]);
    const float iv1 = __expf(-2.0f * log_sigmas[o0 + 1]);

    const size_t waveRow0 = ((size_t)blockIdx.x * WAVES + wv) * (size_t)rows_per_wave;
    const float* p    = x   + waveRow0 * IN_F;
    float*       orow = out + waveRow0 * OUT_F;

    f32x16 alo, ahi, blo, bhi;

    // prologue: row 0 into buffer A
    sload_row(p, alo, ahi);
    wait_smem();

    for (int r = 0; r < rows_per_wave; r += 2) {
        // issue row r+1 into B (rows_per_wave is even, so r+1 is valid)
        sload_row(p + IN_F, blo, bhi);
        compute_row(alo, ahi, c0p, c1p, c2a, c2b, iv0, iv1, orow, o0);
        wait_smem();

        // issue row r+2 into A (guard the final iteration)
        const float* pn = (r + 2 < rows_per_wave) ? (p + 2 * IN_F) : p;
        sload_row(pn, alo, ahi);
        compute_row(blo, bhi, c0p, c1p, c2a, c2b, iv0, iv1, orow + OUT_F, o0);
        wait_smem();

        p    += 2 * IN_F;
        orow += 2 * OUT_F;
    }
}

extern "C" void kernel_launch(void* const* d_in, const int* in_sizes, int n_in,
                              void* d_out, int out_size, void* d_ws, size_t ws_size,
                              hipStream_t stream) {
    const float* x          = (const float*)d_in[0];
    const float* centres    = (const float*)d_in[1];
    const float* log_sigmas = (const float*)d_in[2];
    float* out = (float*)d_out;

    const int n = in_sizes[0] / IN_F;                   // 1,048,576 rows
    const int blocks = 4096;
    const int rows_per_wave = n / (blocks * WAVES);     // 64 (even)
    rbf_kernel<<<blocks, BLOCK, 0, stream>>>(x, centres, log_sigmas, out, rows_per_wave);
}